// Round 13
// baseline (4338.011 us; speedup 1.0000x reference)
//
#include <hip/hip_runtime.h>

// Semi-CRF log-partition. B=4, T=512, L=96, W=63.
// v13: 1024-thread blocks (16 waves, VGPR<=128 via launch_bounds -> 16 w/CU).
// Finalizer: CORE full-rate (waves 0,1, v11-proven); ALL other stages at HALF
// rate via parity x half split: d2 (w2-5), d3 (w6-9), REST chains+z (w10-13).
// Producers' spins use s_sleep(1) (slack-tolerant, cuts issue contention);
// core spins tight. Relays: v11 parity-split design, 8 pairs/block, 15 roles.
// Handoffs: 8B relaxed agent atomics (axp NaN sentinel, chain tag in low 8
// mantissa bits of v); LDS flags relaxed + lgkmcnt(0) only.

#define Tn 512
#define Ln 96
#define HL 48
#define LSQ (Ln * Ln)
#define Wn 63
#define KCH 8
#define NROLE 16  // 1 finalizer + 15 relay roles (8 pair-units each) per batch
#define NEGINF (-1e30f)
#define SENT 0x7FC00000u

#define AGENT __HIP_MEMORY_SCOPE_AGENT
#define WG __HIP_MEMORY_SCOPE_WORKGROUP
#define RLX __ATOMIC_RELAXED
#define LDSF() asm volatile("s_waitcnt lgkmcnt(0)" ::: "memory")
#define CBAR() asm volatile("" ::: "memory")
#define SIDX(b, i, t) ((((size_t)(b) * Tn + (i)) * Tn + (t)) * Ln)

typedef unsigned long long u64;
typedef unsigned int u32;

__device__ __forceinline__ float wsumred(float v) {
#pragma unroll
  for (int m = 32; m >= 1; m >>= 1) v += __shfl_xor(v, m, 64);
  return v;
}
__device__ __forceinline__ u64 pack2(float lo, float hi) {
  return (u64)__float_as_uint(lo) | ((u64)__float_as_uint(hi) << 32);
}
__device__ __forceinline__ float wavemax48(float v) {
  int x;
  x = __builtin_amdgcn_update_dpp(__float_as_int(v), __float_as_int(v), 0xB1,
                                  0xF, 0xF, false);
  v = fmaxf(v, __int_as_float(x));
  x = __builtin_amdgcn_update_dpp(__float_as_int(v), __float_as_int(v), 0x4E,
                                  0xF, 0xF, false);
  v = fmaxf(v, __int_as_float(x));
  x = __builtin_amdgcn_update_dpp(__float_as_int(v), __float_as_int(v), 0x141,
                                  0xF, 0xF, false);
  v = fmaxf(v, __int_as_float(x));
  x = __builtin_amdgcn_update_dpp(__float_as_int(v), __float_as_int(v), 0x140,
                                  0xF, 0xF, false);
  v = fmaxf(v, __int_as_float(x));
  float r0 = __int_as_float(__builtin_amdgcn_readlane(__float_as_int(v), 0));
  float r1 = __int_as_float(__builtin_amdgcn_readlane(__float_as_int(v), 16));
  float r2 = __int_as_float(__builtin_amdgcn_readlane(__float_as_int(v), 32));
  float r3 = __int_as_float(__builtin_amdgcn_readlane(__float_as_int(v), 48));
  return fmaxf(fmaxf(r0, r1), fmaxf(r2, r3));
}
__device__ __forceinline__ float comb(float Slo, float Shi, float C0, float C1,
                                      float wseg) {
  const float Cm = fmaxf(C0, C1);
  return Cm + wseg + __logf(__expf(C0 - Cm) * Slo + __expf(C1 - Cm) * Shi);
}

#define MV1(SRC, RR, SLO, SHI)                                       \
  float SLO, SHI;                                                    \
  {                                                                  \
    const float4* A4 = (const float4*)(SRC);                         \
    float a0 = 0, a1 = 0, a2 = 0, a3 = 0;                            \
    _Pragma("unroll") for (int q = 0; q < 12; ++q) {                 \
      float4 a = A4[q];                                              \
      a0 = fmaf(a.x, RR[4 * q + 0], a0);                             \
      a1 = fmaf(a.y, RR[4 * q + 1], a1);                             \
      a2 = fmaf(a.z, RR[4 * q + 2], a2);                             \
      a3 = fmaf(a.w, RR[4 * q + 3], a3);                             \
    }                                                                \
    SLO = (a0 + a1) + (a2 + a3);                                     \
    float b0 = 0, b1 = 0, b2 = 0, b3 = 0;                            \
    _Pragma("unroll") for (int q = 12; q < 24; ++q) {                \
      float4 a = A4[q];                                              \
      b0 = fmaf(a.x, RR[4 * q + 0], b0);                             \
      b1 = fmaf(a.y, RR[4 * q + 1], b1);                             \
      b2 = fmaf(a.z, RR[4 * q + 2], b2);                             \
      b3 = fmaf(a.w, RR[4 * q + 3], b3);                             \
    }                                                                \
    SHI = (b0 + b1) + (b2 + b3);                                     \
  }

#define SLEEPSPIN(COND) \
  while (COND) __builtin_amdgcn_s_sleep(1);

__global__ void init_ws(u64* ws) {
  const size_t n1 = (size_t)4 * Tn * Ln;
  const size_t n = n1 * 9;  // axp + 8 chains
  for (size_t i = (size_t)blockIdx.x * blockDim.x + threadIdx.x; i < n;
       i += (size_t)gridDim.x * blockDim.x)
    ws[i] = (i < n1) ? (((u64)SENT) << 32) : 0ull;
}

__global__ __launch_bounds__(1024, 4) void semicrf(
    const float* __restrict__ seg, const float* __restrict__ tr,
    float* __restrict__ out, u64* axp, u64* acc) {
  const int b = blockIdx.x / NROLE;
  const int role = blockIdx.x % NROLE;
  const int tid = threadIdx.x;

  __shared__ __align__(16) float E[LSQ];           // exp(trans) 36 KB
  __shared__ __align__(16) float AlbR[8][Ln];      // core alpha ring
  __shared__ float CRng[8][2];                     // per-half C ring
  __shared__ __align__(16) float slotC2[4][Ln];    // d2 contributions
  __shared__ __align__(16) float slotC3[4][Ln];    // d3 contributions
  __shared__ float RESTm[4][Ln];                   // chains+z merge (m)
  __shared__ float RESTv[4][Ln];                   // chains+z merge (v)
  __shared__ __align__(16) float Alb_s[8][2][Ln];  // relay staging (dbuf)
  __shared__ float CstS[8][2][2];
  __shared__ float redbuf[2];
  __shared__ int seqA[2], sp2[2][2], sp3[2][2], rq[2][2], rfl[2];
  __shared__ int stg[8][2];

  if (tid < 2) { seqA[tid] = -1; rfl[tid] = -1; }
  if (tid < 4) {
    sp2[tid >> 1][tid & 1] = -1;
    sp3[tid >> 1][tid & 1] = -1;
    rq[tid >> 1][tid & 1] = -1;
  }
  if (tid < 16) stg[tid >> 1][tid & 1] = -1;
  for (int i = tid; i < LSQ; i += 1024) E[i] = __expf(tr[i]);
  __syncthreads();  // the only block-wide barrier

  if (role != 0) {
    // ====== relay pair-unit: pu=(role-1)*8+pair -> d=4+pu/2, parity pu&1 ====
    const int pair = tid >> 7;
    const int tp = tid & 127;
    const int wv = tp >> 6;
    const int rl = tp & 63;
    const bool act = rl < HL;
    const int lab = wv * HL + (act ? rl : HL - 1);
    const int pu = (role - 1) * 8 + pair;
    const int d = 4 + (pu >> 1);
    const int par = pu & 1;
    const int j = d & 7;
    u64* chain = acc + (size_t)(j * 4 + b) * Tn * Ln;
    const u64* axB = axp + (size_t)b * Tn * Ln;
    float R[Ln];
#pragma unroll
    for (int lp = 0; lp < Ln; ++lp) R[lp] = E[lp * Ln + lab];
    int wc = 1;
    const bool aHead = (d + KCH > Wn);
    const int t0 = d + (((d ^ par) & 1) ? 1 : 0);

    for (int t = t0; t < Tn; t += 2) {
      const int s = t - d;
      const int w = (t <= Wn) ? (s + 1) : (64 - d);
      while (w > wc) {
        ++wc;
#pragma unroll
        for (int lp = 0; lp < Ln; ++lp) R[lp] *= E[lp * Ln + lab];
      }
      const float segv = seg[SIDX(b, s + 1, t) + lab];
      const size_t tIdx = (size_t)t * Ln + lab;
      const bool head = aHead || (s < KCH);
      u64 ua = 0;
      if (!head) ua = __hip_atomic_load(&chain[tIdx], RLX, AGENT);

      u64 up = __hip_atomic_load(&axB[(size_t)s * Ln + lab], RLX, AGENT);
      while ((u32)(up >> 32) == SENT)
        up = __hip_atomic_load(&axB[(size_t)s * Ln + lab], RLX, AGENT);

      const int buf = (t >> 1) & 1;
      if (act) Alb_s[pair][buf][lab] = __uint_as_float((u32)up);
      if (rl == 0) CstS[pair][buf][wv] = __uint_as_float((u32)(up >> 32));
      LDSF();
      __hip_atomic_store(&stg[pair][wv], t, RLX, WG);
      while (__hip_atomic_load(&stg[pair][wv ^ 1], RLX, WG) < t) {}
      CBAR();
      const float C0 = CstS[pair][buf][0], C1 = CstS[pair][buf][1];
      MV1(Alb_s[pair][buf], R, Slo, Shi)
      const float c = comb(Slo, Shi, C0, C1, (float)w * segv);

      float m, v;
      if (head) {
        m = c;
        v = 1.f;
      } else {
        while (((ua >> 32) & 0xFFu) != (u32)(d + KCH))
          ua = __hip_atomic_load(&chain[tIdx], RLX, AGENT);
        const float pm = __uint_as_float((u32)ua);
        const float pv = __uint_as_float(((u32)(ua >> 32)) & ~0xFFu);
        const float nm = fmaxf(pm, c);
        v = pv * __expf(pm - nm) + __expf(c - nm);
        m = nm;
      }
      if (act) {
        const u32 vb = (__float_as_uint(v) & ~0xFFu) | (u32)d;
        __hip_atomic_store(&chain[tIdx],
                           (u64)__float_as_uint(m) | ((u64)vb << 32), RLX,
                           AGENT);
      }
    }
    return;
  }

  // =========================== finalizer block =============================
  const int w6 = tid >> 6;
  const int l = tid & 63;
  const bool act = l < HL;

  if (w6 < 2) {
    // ---- CORE wave h: d=1 matvec + merge {c1,c2,c3,REST} + publish --------
    const int h = w6;
    const int lab = h * HL + (act ? l : HL - 1);
    u64* axpB = axp + (size_t)b * Tn * Ln;
    float R1[Ln];
#pragma unroll
    for (int lp = 0; lp < Ln; ++lp) R1[lp] = E[lp * Ln + lab];
    int w1c = 1;
    {  // seed t=0: alpha0 = exp(seg[b,0,0,:]+bos) (reference stores exp'd)
      const float bos = tr[LSQ + lab];
      const float a0 = __expf(seg[SIDX(b, 0, 0) + lab] + bos);
      const float Cw = wavemax48(act ? a0 : NEGINF);
      const float ax0 = __expf(a0 - Cw);
      if (act) AlbR[0][lab] = ax0;
      if (l == 0) CRng[0][h] = Cw;
      LDSF();
      __hip_atomic_store(&seqA[h], 0, RLX, WG);
      if (act) __hip_atomic_store(&axpB[lab], pack2(ax0, Cw), RLX, AGENT);
    }
    float s1q0 = seg[SIDX(b, 1, 1) + lab];
    float s1q1 = seg[SIDX(b, 2, 2) + lab];

    for (int t = 1; t < Tn; ++t) {
      const int s = t - 1;
      const float s1 = s1q0;
      s1q0 = s1q1;
      if (t + 2 < Tn) s1q1 = seg[SIDX(b, t + 2, t + 2) + lab];
      const int w1 = (t <= Wn) ? t : Wn;
      if (w1 > w1c) {
        w1c = w1;
#pragma unroll
        for (int lp = 0; lp < Ln; ++lp) R1[lp] *= E[lp * Ln + lab];
      }
      while (__hip_atomic_load(&seqA[h ^ 1], RLX, WG) < s) {}
      CBAR();
      const float C0 = CRng[s & 7][0], C1 = CRng[s & 7][1];
      MV1(AlbR[s & 7], R1, Slo, Shi)
      const float c1 = comb(Slo, Shi, C0, C1, (float)w1 * s1);
      float c2 = NEGINF, c3 = NEGINF;
      if (t >= 2) {
        while (__hip_atomic_load(&sp2[t & 1][h], RLX, WG) < t) {}
        CBAR();
        c2 = slotC2[t & 3][lab];
      }
      if (t >= 3) {
        while (__hip_atomic_load(&sp3[t & 1][h], RLX, WG) < t) {}
        CBAR();
        c3 = slotC3[t & 3][lab];
      }
      while (__hip_atomic_load(&rq[t & 1][h], RLX, WG) < t) {}
      CBAR();
      const float mr = RESTm[t & 3][lab], vr = RESTv[t & 3][lab];
      const float M = fmaxf(fmaxf(c1, c2), fmaxf(c3, mr));
      const float vs = __expf(c1 - M) + __expf(c2 - M) + __expf(c3 - M) +
                       vr * __expf(mr - M);
      const float alpha = M + __logf(vs);
      const float Cw = wavemax48(act ? alpha : NEGINF);
      const float axn = __expf(alpha - Cw);
      if (act) AlbR[t & 7][lab] = axn;
      if (l == 0) CRng[t & 7][h] = Cw;
      LDSF();
      __hip_atomic_store(&seqA[h], t, RLX, WG);
      if (act)
        __hip_atomic_store(&axpB[(size_t)t * Ln + lab], pack2(axn, Cw), RLX,
                           AGENT);
      if (t == Tn - 1) {
        const float sm = wsumred(act ? axn : 0.f);
        const float Gw = Cw + __logf(sm);
        if (l == 0) redbuf[h] = Gw;
        LDSF();
        __hip_atomic_store(&rfl[h], 1, RLX, WG);
        if (h == 0 && l == 0) {
          while (__hip_atomic_load(&rfl[1], RLX, WG) < 1) {}
          CBAR();
          const float G0 = redbuf[0], G1 = redbuf[1];
          const float Mx = fmaxf(G0, G1);
          out[b] = Mx + __logf(__expf(G0 - Mx) + __expf(G1 - Mx));
        }
      }
    }
    return;
  }

  if (w6 < 6) {
    // ---- d2 wave: parity p, half h; targets t = t0, t0+2, ... -------------
    const int p = (w6 - 2) >> 1;
    const int h = (w6 - 2) & 1;
    const int lab = h * HL + (act ? l : HL - 1);
    float R[Ln];
#pragma unroll
    for (int lp = 0; lp < Ln; ++lp) R[lp] = E[lp * Ln + lab];
    int wc = 1;
    const int t0 = 2 + p;
    float q0 = seg[SIDX(b, t0 - 1, t0) + lab];
    float q1 = (t0 + 2 < Tn) ? seg[SIDX(b, t0 + 1, t0 + 2) + lab] : 0.f;

    for (int t = t0; t < Tn; t += 2) {
      const int s = t - 2;
      const int w = (t <= Wn) ? (s + 1) : 62;
      const float segv = q0;
      q0 = q1;
      if (t + 4 < Tn) q1 = seg[SIDX(b, t + 3, t + 4) + lab];
      while (w > wc) {
        ++wc;
#pragma unroll
        for (int lp = 0; lp < Ln; ++lp) R[lp] *= E[lp * Ln + lab];
      }
      SLEEPSPIN(__hip_atomic_load(&seqA[0], RLX, WG) < s ||
                __hip_atomic_load(&seqA[1], RLX, WG) < s)
      CBAR();
      const float C0 = CRng[s & 7][0], C1 = CRng[s & 7][1];
      MV1(AlbR[s & 7], R, Slo, Shi)
      const float c = comb(Slo, Shi, C0, C1, (float)w * segv);
      if (act) slotC2[t & 3][lab] = c;
      LDSF();
      __hip_atomic_store(&sp2[p][h], t, RLX, WG);
    }
    return;
  }

  if (w6 < 10) {
    // ---- d3 wave: parity p, half h ----------------------------------------
    const int p = (w6 - 6) >> 1;
    const int h = (w6 - 6) & 1;
    const int lab = h * HL + (act ? l : HL - 1);
    float R[Ln];
#pragma unroll
    for (int lp = 0; lp < Ln; ++lp) R[lp] = E[lp * Ln + lab];
    int wc = 1;
    const int t0 = (p == 1) ? 3 : 4;
    float q0 = seg[SIDX(b, t0 - 2, t0) + lab];
    float q1 = (t0 + 2 < Tn) ? seg[SIDX(b, t0, t0 + 2) + lab] : 0.f;

    for (int t = t0; t < Tn; t += 2) {
      const int s = t - 3;
      const int w = (t <= Wn) ? (s + 1) : 61;
      const float segv = q0;
      q0 = q1;
      if (t + 4 < Tn) q1 = seg[SIDX(b, t + 2, t + 4) + lab];
      while (w > wc) {
        ++wc;
#pragma unroll
        for (int lp = 0; lp < Ln; ++lp) R[lp] *= E[lp * Ln + lab];
      }
      SLEEPSPIN(__hip_atomic_load(&seqA[0], RLX, WG) < s ||
                __hip_atomic_load(&seqA[1], RLX, WG) < s)
      CBAR();
      const float C0 = CRng[s & 7][0], C1 = CRng[s & 7][1];
      MV1(AlbR[s & 7], R, Slo, Shi)
      const float c = comb(Slo, Shi, C0, C1, (float)w * segv);
      if (act) slotC3[t & 3][lab] = c;
      LDSF();
      __hip_atomic_store(&sp3[p][h], t, RLX, WG);
    }
    return;
  }

  if (w6 < 14) {
    // ---- REST wave: parity p, half h; 8 chain ends + z --------------------
    const int p = (w6 - 10) >> 1;
    const int h = (w6 - 10) & 1;
    const int lab = h * HL + (act ? l : HL - 1);
    const float bos = tr[LSQ + lab];
    const int endd[8] = {8, 9, 10, 11, 4, 5, 6, 7};  // chain end per residue
    const int t0 = (p == 1) ? 1 : 2;
    float zq0 = seg[SIDX(b, 0, t0) + lab];
    float zq1 = (t0 + 2 <= Wn) ? seg[SIDX(b, 0, t0 + 2) + lab] : 0.f;
    u64 u[8];
#pragma unroll
    for (int jj = 0; jj < 8; ++jj) {
      u[jj] = 0;
      if (t0 >= endd[jj])
        u[jj] = __hip_atomic_load(
            &acc[(((size_t)jj * 4 + b) * Tn + t0) * Ln + lab], RLX, AGENT);
    }

    for (int t = t0; t < Tn; t += 2) {
      const float szv = zq0;
      zq0 = zq1;
      if (t + 4 <= Wn) zq1 = seg[SIDX(b, 0, t + 4) + lab];

      float em[8], ev[8];
#pragma unroll
      for (int jj = 0; jj < 8; ++jj) {
        if (t >= endd[jj]) {
          const size_t aIdx = (((size_t)jj * 4 + b) * Tn + t) * Ln + lab;
          while (((u[jj] >> 32) & 0xFFu) != (u32)endd[jj])
            u[jj] = __hip_atomic_load(&acc[aIdx], RLX, AGENT);
          em[jj] = __uint_as_float((u32)u[jj]);
          ev[jj] = __uint_as_float(((u32)(u[jj] >> 32)) & ~0xFFu);
        } else {
          em[jj] = NEGINF;
          ev[jj] = 0.f;
        }
      }
      const float zv = (t <= Wn) ? (float)(t + 1) * (szv + bos) : NEGINF;

      float M = zv;
#pragma unroll
      for (int jj = 0; jj < 8; ++jj) M = fmaxf(M, em[jj]);
      float vs = __expf(zv - M);
#pragma unroll
      for (int jj = 0; jj < 8; ++jj) vs += ev[jj] * __expf(em[jj] - M);

      if (act) {
        RESTm[t & 3][lab] = M;
        RESTv[t & 3][lab] = vs;
      }
      LDSF();
      __hip_atomic_store(&rq[p][h], t, RLX, WG);

      const int tn = t + 2;  // depth-1 prefetch (stride 2)
      if (tn < Tn) {
#pragma unroll
        for (int jj = 0; jj < 8; ++jj)
          if (tn >= endd[jj])
            u[jj] = __hip_atomic_load(
                &acc[(((size_t)jj * 4 + b) * Tn + tn) * Ln + lab], RLX, AGENT);
      }
    }
    return;
  }
  return;  // waves 14,15 idle
}

extern "C" void kernel_launch(void* const* d_in, const int* in_sizes, int n_in,
                              void* d_out, int out_size, void* d_ws,
                              size_t ws_size, hipStream_t stream) {
  const float* seg = (const float*)d_in[0];  // (4,512,512,96) f32
  const float* tr = (const float*)d_in[1];   // (97,96) f32
  float* out = (float*)d_out;                // (4,) f32

  u64* axp = (u64*)d_ws;                 // [4][512][96]
  u64* acc = axp + (size_t)4 * Tn * Ln;  // [8][4][512][96]

  hipLaunchKernelGGL(init_ws, dim3(2048), dim3(256), 0, stream, (u64*)d_ws);
  hipLaunchKernelGGL(semicrf, dim3(4 * NROLE), dim3(1024), 0, stream, seg, tr,
                     out, axp, acc);
}

// Round 14
// 819.070 us; speedup vs baseline: 5.2963x; 5.2963x over previous
//
#include <hip/hip_runtime.h>

// Semi-CRF log-partition. B=4, T=512, L=96, W=63.
// v14 = v11 topology, finalizer-CU LDS diet (v10/v11 showed finalizer CU is
// the wall; arithmetic says its LDS pipe: 8 waves x 24 ds_read_b128/step).
//  - alpha ring stored as bf16 -> matvec = 12 b128/wave (was 24)
//  - d=3 moved OUT to relay chains (ends d=3..10); REST = chains+z only,
//    no matvec, no seqA wait, depth-1 chain prefetch
//  - d=2 parity x half (4 waves at HALF rate, sleep-spins)
//  - relays d=3..63 parity-split (v11-proven), f32 staging unchanged
// Handoffs: 8B relaxed agent atomics (axp NaN sentinel, chain tag in low 8
// mantissa bits of v); LDS flags relaxed + lgkmcnt(0) only. VGPR=128 (512thr).

#define Tn 512
#define Ln 96
#define HL 48
#define LSQ (Ln * Ln)
#define Wn 63
#define KCH 8
#define NROLE 32  // 1 finalizer + 31 relay roles (4 pair-units each) per batch
#define NEGINF (-1e30f)
#define SENT 0x7FC00000u

#define AGENT __HIP_MEMORY_SCOPE_AGENT
#define WG __HIP_MEMORY_SCOPE_WORKGROUP
#define RLX __ATOMIC_RELAXED
#define LDSF() asm volatile("s_waitcnt lgkmcnt(0)" ::: "memory")
#define CBAR() asm volatile("" ::: "memory")
#define SIDX(b, i, t) ((((size_t)(b) * Tn + (i)) * Tn + (t)) * Ln)
#define SLEEPSPIN(COND) \
  while (COND) __builtin_amdgcn_s_sleep(1);

typedef unsigned long long u64;
typedef unsigned int u32;
typedef unsigned short u16;

__device__ __forceinline__ float wsumred(float v) {
#pragma unroll
  for (int m = 32; m >= 1; m >>= 1) v += __shfl_xor(v, m, 64);
  return v;
}
__device__ __forceinline__ u64 pack2(float lo, float hi) {
  return (u64)__float_as_uint(lo) | ((u64)__float_as_uint(hi) << 32);
}
__device__ __forceinline__ u16 tobf16(float x) {
  return (u16)((__float_as_uint(x) + 0x8000u) >> 16);
}
__device__ __forceinline__ float wavemax48(float v) {
  int x;
  x = __builtin_amdgcn_update_dpp(__float_as_int(v), __float_as_int(v), 0xB1,
                                  0xF, 0xF, false);
  v = fmaxf(v, __int_as_float(x));
  x = __builtin_amdgcn_update_dpp(__float_as_int(v), __float_as_int(v), 0x4E,
                                  0xF, 0xF, false);
  v = fmaxf(v, __int_as_float(x));
  x = __builtin_amdgcn_update_dpp(__float_as_int(v), __float_as_int(v), 0x141,
                                  0xF, 0xF, false);
  v = fmaxf(v, __int_as_float(x));
  x = __builtin_amdgcn_update_dpp(__float_as_int(v), __float_as_int(v), 0x140,
                                  0xF, 0xF, false);
  v = fmaxf(v, __int_as_float(x));
  float r0 = __int_as_float(__builtin_amdgcn_readlane(__float_as_int(v), 0));
  float r1 = __int_as_float(__builtin_amdgcn_readlane(__float_as_int(v), 16));
  float r2 = __int_as_float(__builtin_amdgcn_readlane(__float_as_int(v), 32));
  float r3 = __int_as_float(__builtin_amdgcn_readlane(__float_as_int(v), 48));
  return fmaxf(fmaxf(r0, r1), fmaxf(r2, r3));
}
__device__ __forceinline__ float comb(float Slo, float Shi, float C0, float C1,
                                      float wseg) {
  const float Cm = fmaxf(C0, C1);
  return Cm + wseg + __logf(__expf(C0 - Cm) * Slo + __expf(C1 - Cm) * Shi);
}

// f32 matvec (relays): 24 ds_read_b128
#define MV1(SRC, RR, SLO, SHI)                                       \
  float SLO, SHI;                                                    \
  {                                                                  \
    const float4* A4 = (const float4*)(SRC);                         \
    float a0 = 0, a1 = 0, a2 = 0, a3 = 0;                            \
    _Pragma("unroll") for (int q = 0; q < 12; ++q) {                 \
      float4 a = A4[q];                                              \
      a0 = fmaf(a.x, RR[4 * q + 0], a0);                             \
      a1 = fmaf(a.y, RR[4 * q + 1], a1);                             \
      a2 = fmaf(a.z, RR[4 * q + 2], a2);                             \
      a3 = fmaf(a.w, RR[4 * q + 3], a3);                             \
    }                                                                \
    SLO = (a0 + a1) + (a2 + a3);                                     \
    float b0 = 0, b1 = 0, b2 = 0, b3 = 0;                            \
    _Pragma("unroll") for (int q = 12; q < 24; ++q) {                \
      float4 a = A4[q];                                              \
      b0 = fmaf(a.x, RR[4 * q + 0], b0);                             \
      b1 = fmaf(a.y, RR[4 * q + 1], b1);                             \
      b2 = fmaf(a.z, RR[4 * q + 2], b2);                             \
      b3 = fmaf(a.w, RR[4 * q + 3], b3);                             \
    }                                                                \
    SHI = (b0 + b1) + (b2 + b3);                                     \
  }

// bf16 matvec (finalizer): 12 ds_read_b128, shift/and unpack
#define MVB(SRC, RR, SLO, SHI)                                               \
  float SLO, SHI;                                                            \
  {                                                                          \
    const uint4* A4 = (const uint4*)(SRC);                                   \
    float a0 = 0, a1 = 0, a2 = 0, a3 = 0;                                    \
    _Pragma("unroll") for (int q = 0; q < 6; ++q) {                          \
      uint4 a = A4[q];                                                       \
      a0 = fmaf(__uint_as_float(a.x << 16), RR[8 * q + 0], a0);              \
      a1 = fmaf(__uint_as_float(a.x & 0xFFFF0000u), RR[8 * q + 1], a1);      \
      a2 = fmaf(__uint_as_float(a.y << 16), RR[8 * q + 2], a2);              \
      a3 = fmaf(__uint_as_float(a.y & 0xFFFF0000u), RR[8 * q + 3], a3);      \
      a0 = fmaf(__uint_as_float(a.z << 16), RR[8 * q + 4], a0);              \
      a1 = fmaf(__uint_as_float(a.z & 0xFFFF0000u), RR[8 * q + 5], a1);      \
      a2 = fmaf(__uint_as_float(a.w << 16), RR[8 * q + 6], a2);              \
      a3 = fmaf(__uint_as_float(a.w & 0xFFFF0000u), RR[8 * q + 7], a3);      \
    }                                                                        \
    SLO = (a0 + a1) + (a2 + a3);                                             \
    float b0 = 0, b1 = 0, b2 = 0, b3 = 0;                                    \
    _Pragma("unroll") for (int q = 6; q < 12; ++q) {                         \
      uint4 a = A4[q];                                                       \
      b0 = fmaf(__uint_as_float(a.x << 16), RR[8 * q + 0], b0);              \
      b1 = fmaf(__uint_as_float(a.x & 0xFFFF0000u), RR[8 * q + 1], b1);      \
      b2 = fmaf(__uint_as_float(a.y << 16), RR[8 * q + 2], b2);              \
      b3 = fmaf(__uint_as_float(a.y & 0xFFFF0000u), RR[8 * q + 3], b3);      \
      b0 = fmaf(__uint_as_float(a.z << 16), RR[8 * q + 4], b0);              \
      b1 = fmaf(__uint_as_float(a.z & 0xFFFF0000u), RR[8 * q + 5], b1);      \
      b2 = fmaf(__uint_as_float(a.w << 16), RR[8 * q + 6], b2);              \
      b3 = fmaf(__uint_as_float(a.w & 0xFFFF0000u), RR[8 * q + 7], b3);      \
    }                                                                        \
    SHI = (b0 + b1) + (b2 + b3);                                             \
  }

__global__ void init_ws(u64* ws) {
  const size_t n1 = (size_t)4 * Tn * Ln;
  const size_t n = n1 * 9;  // axp + 8 chains
  for (size_t i = (size_t)blockIdx.x * blockDim.x + threadIdx.x; i < n;
       i += (size_t)gridDim.x * blockDim.x)
    ws[i] = (i < n1) ? (((u64)SENT) << 32) : 0ull;
}

__global__ __launch_bounds__(512, 1) void semicrf(
    const float* __restrict__ seg, const float* __restrict__ tr,
    float* __restrict__ out, u64* axp, u64* acc) {
  const int b = blockIdx.x / NROLE;
  const int role = blockIdx.x % NROLE;
  const int tid = threadIdx.x;

  __shared__ __align__(16) float E[LSQ];           // exp(trans) 36 KB
  __shared__ __align__(16) u16 AlbRh[8][Ln];       // bf16 alpha ring
  __shared__ float CRng[8][2];                     // per-half C ring
  __shared__ __align__(16) float slotC2[4][Ln];    // d2 contributions
  __shared__ float RESTm[4][Ln];                   // chains+z merge (m)
  __shared__ float RESTv[4][Ln];                   // chains+z merge (v)
  __shared__ __align__(16) float Alb_s[4][2][Ln];  // relay staging (dbuf)
  __shared__ float CstS[4][2][2];
  __shared__ float redbuf[2];
  __shared__ int seqA[2], sp2[2][2], rq[2], rfl[2];
  __shared__ int stg[4][2];

  if (tid < 2) { seqA[tid] = -1; rq[tid] = -1; rfl[tid] = -1; }
  if (tid < 4) sp2[tid >> 1][tid & 1] = -1;
  if (tid < 8) stg[tid >> 1][tid & 1] = -1;
  for (int i = tid; i < LSQ; i += 512) E[i] = __expf(tr[i]);
  __syncthreads();  // the only block-wide barrier

  if (role != 0) {
    // == relay pair-unit: pu=(role-1)*4+pair -> d=3+pu/2, parity pu&1 ========
    const int pair = tid >> 7;
    const int tp = tid & 127;
    const int wv = tp >> 6;
    const int rl = tp & 63;
    const bool act = rl < HL;
    const int lab = wv * HL + (act ? rl : HL - 1);
    const int pu = (role - 1) * 4 + pair;
    if (pu >= 122) return;  // after barrier: safe
    const int d = 3 + (pu >> 1);
    const int par = pu & 1;
    const int j = d & 7;
    u64* chain = acc + (size_t)(j * 4 + b) * Tn * Ln;
    const u64* axB = axp + (size_t)b * Tn * Ln;
    float R[Ln];
#pragma unroll
    for (int lp = 0; lp < Ln; ++lp) R[lp] = E[lp * Ln + lab];
    int wc = 1;
    const bool aHead = (d + KCH > Wn);
    const int t0 = d + (((d ^ par) & 1) ? 1 : 0);

    for (int t = t0; t < Tn; t += 2) {
      const int s = t - d;
      const int w = (t <= Wn) ? (s + 1) : (64 - d);
      while (w > wc) {
        ++wc;
#pragma unroll
        for (int lp = 0; lp < Ln; ++lp) R[lp] *= E[lp * Ln + lab];
      }
      const float segv = seg[SIDX(b, s + 1, t) + lab];
      const size_t tIdx = (size_t)t * Ln + lab;
      const bool head = aHead || (s < KCH);
      u64 ua = 0;
      if (!head) ua = __hip_atomic_load(&chain[tIdx], RLX, AGENT);

      u64 up = __hip_atomic_load(&axB[(size_t)s * Ln + lab], RLX, AGENT);
      while ((u32)(up >> 32) == SENT)
        up = __hip_atomic_load(&axB[(size_t)s * Ln + lab], RLX, AGENT);

      const int buf = (t >> 1) & 1;
      if (act) Alb_s[pair][buf][lab] = __uint_as_float((u32)up);
      if (rl == 0) CstS[pair][buf][wv] = __uint_as_float((u32)(up >> 32));
      LDSF();
      __hip_atomic_store(&stg[pair][wv], t, RLX, WG);
      while (__hip_atomic_load(&stg[pair][wv ^ 1], RLX, WG) < t) {}
      CBAR();
      const float C0 = CstS[pair][buf][0], C1 = CstS[pair][buf][1];
      MV1(Alb_s[pair][buf], R, Slo, Shi)
      const float c = comb(Slo, Shi, C0, C1, (float)w * segv);

      float m, v;
      if (head) {
        m = c;
        v = 1.f;
      } else {
        while (((ua >> 32) & 0xFFu) != (u32)(d + KCH))
          ua = __hip_atomic_load(&chain[tIdx], RLX, AGENT);
        const float pm = __uint_as_float((u32)ua);
        const float pv = __uint_as_float(((u32)(ua >> 32)) & ~0xFFu);
        const float nm = fmaxf(pm, c);
        v = pv * __expf(pm - nm) + __expf(c - nm);
        m = nm;
      }
      if (act) {
        const u32 vb = (__float_as_uint(v) & ~0xFFu) | (u32)d;
        __hip_atomic_store(&chain[tIdx],
                           (u64)__float_as_uint(m) | ((u64)vb << 32), RLX,
                           AGENT);
      }
    }
    return;
  }

  // =========================== finalizer block =============================
  const int w6 = tid >> 6;
  const int l = tid & 63;
  const bool act = l < HL;

  if (w6 < 2) {
    // ---- CORE wave h: bf16 matvec + merge {c1, c2, REST} + publish --------
    const int h = w6;
    const int lab = h * HL + (act ? l : HL - 1);
    u64* axpB = axp + (size_t)b * Tn * Ln;
    float R1[Ln];
#pragma unroll
    for (int lp = 0; lp < Ln; ++lp) R1[lp] = E[lp * Ln + lab];
    int w1c = 1;
    {  // seed t=0: alpha0 = exp(seg[b,0,0,:]+bos) (reference stores exp'd)
      const float bos = tr[LSQ + lab];
      const float a0 = __expf(seg[SIDX(b, 0, 0) + lab] + bos);
      const float Cw = wavemax48(act ? a0 : NEGINF);
      const float ax0 = __expf(a0 - Cw);
      if (act) AlbRh[0][lab] = tobf16(ax0);
      if (l == 0) CRng[0][h] = Cw;
      LDSF();
      __hip_atomic_store(&seqA[h], 0, RLX, WG);
      if (act) __hip_atomic_store(&axpB[lab], pack2(ax0, Cw), RLX, AGENT);
    }
    float s1q0 = seg[SIDX(b, 1, 1) + lab];
    float s1q1 = seg[SIDX(b, 2, 2) + lab];

    for (int t = 1; t < Tn; ++t) {
      const int s = t - 1;
      const float s1 = s1q0;
      s1q0 = s1q1;
      if (t + 2 < Tn) s1q1 = seg[SIDX(b, t + 2, t + 2) + lab];
      const int w1 = (t <= Wn) ? t : Wn;
      if (w1 > w1c) {
        w1c = w1;
#pragma unroll
        for (int lp = 0; lp < Ln; ++lp) R1[lp] *= E[lp * Ln + lab];
      }
      while (__hip_atomic_load(&seqA[h ^ 1], RLX, WG) < s) {}
      CBAR();
      const float C0 = CRng[s & 7][0], C1 = CRng[s & 7][1];
      MVB(AlbRh[s & 7], R1, Slo, Shi)
      const float c1 = comb(Slo, Shi, C0, C1, (float)w1 * s1);
      float c2 = NEGINF;
      if (t >= 2) {
        while (__hip_atomic_load(&sp2[t & 1][h], RLX, WG) < t) {}
        CBAR();
        c2 = slotC2[t & 3][lab];
      }
      while (__hip_atomic_load(&rq[h], RLX, WG) < t) {}
      CBAR();
      const float mr = RESTm[t & 3][lab], vr = RESTv[t & 3][lab];
      const float M = fmaxf(fmaxf(c1, c2), mr);
      const float vs = __expf(c1 - M) + __expf(c2 - M) + vr * __expf(mr - M);
      const float alpha = M + __logf(vs);
      const float Cw = wavemax48(act ? alpha : NEGINF);
      const float axn = __expf(alpha - Cw);
      if (act) AlbRh[t & 7][lab] = tobf16(axn);
      if (l == 0) CRng[t & 7][h] = Cw;
      LDSF();
      __hip_atomic_store(&seqA[h], t, RLX, WG);
      if (act)
        __hip_atomic_store(&axpB[(size_t)t * Ln + lab], pack2(axn, Cw), RLX,
                           AGENT);
      if (t == Tn - 1) {
        const float sm = wsumred(act ? axn : 0.f);
        const float Gw = Cw + __logf(sm);
        if (l == 0) redbuf[h] = Gw;
        LDSF();
        __hip_atomic_store(&rfl[h], 1, RLX, WG);
        if (h == 0 && l == 0) {
          while (__hip_atomic_load(&rfl[1], RLX, WG) < 1) {}
          CBAR();
          const float G0 = redbuf[0], G1 = redbuf[1];
          const float Mx = fmaxf(G0, G1);
          out[b] = Mx + __logf(__expf(G0 - Mx) + __expf(G1 - Mx));
        }
      }
    }
    return;
  }

  if (w6 < 6) {
    // ---- d2 wave: parity p, half h; HALF rate (stride 2) ------------------
    const int p = (w6 - 2) >> 1;
    const int h = (w6 - 2) & 1;
    const int lab = h * HL + (act ? l : HL - 1);
    float R[Ln];
#pragma unroll
    for (int lp = 0; lp < Ln; ++lp) R[lp] = E[lp * Ln + lab];
    int wc = 1;
    const int t0 = 2 + p;
    float q0 = seg[SIDX(b, t0 - 1, t0) + lab];
    float q1 = (t0 + 2 < Tn) ? seg[SIDX(b, t0 + 1, t0 + 2) + lab] : 0.f;

    for (int t = t0; t < Tn; t += 2) {
      const int s = t - 2;
      const int w = (t <= Wn) ? (s + 1) : 62;
      const float segv = q0;
      q0 = q1;
      if (t + 4 < Tn) q1 = seg[SIDX(b, t + 3, t + 4) + lab];
      while (w > wc) {
        ++wc;
#pragma unroll
        for (int lp = 0; lp < Ln; ++lp) R[lp] *= E[lp * Ln + lab];
      }
      SLEEPSPIN(__hip_atomic_load(&seqA[0], RLX, WG) < s ||
                __hip_atomic_load(&seqA[1], RLX, WG) < s)
      CBAR();
      const float C0 = CRng[s & 7][0], C1 = CRng[s & 7][1];
      MVB(AlbRh[s & 7], R, Slo, Shi)
      const float c = comb(Slo, Shi, C0, C1, (float)w * segv);
      if (act) slotC2[t & 3][lab] = c;
      LDSF();
      __hip_atomic_store(&sp2[p][h], t, RLX, WG);
    }
    return;
  }

  {
    // ---- REST wave h (w6=6,7): 8 chain ends + z; no matvec, no seqA wait --
    const int h = w6 - 6;
    const int lab = h * HL + (act ? l : HL - 1);
    const float bos = tr[LSQ + lab];
    const int endd[8] = {8, 9, 10, 3, 4, 5, 6, 7};  // chain end per residue
    float zq0 = seg[SIDX(b, 0, 1) + lab];
    float zq1 = seg[SIDX(b, 0, 2) + lab];
    u64 u[8];
#pragma unroll
    for (int jj = 0; jj < 8; ++jj) u[jj] = 0;

    for (int t = 1; t < Tn; ++t) {
      const float szv = zq0;
      zq0 = zq1;
      if (t + 2 <= Wn) zq1 = seg[SIDX(b, 0, t + 2) + lab];

      float em[8], ev[8];
#pragma unroll
      for (int jj = 0; jj < 8; ++jj) {
        if (t >= endd[jj]) {
          const size_t aIdx = (((size_t)jj * 4 + b) * Tn + t) * Ln + lab;
          while (((u[jj] >> 32) & 0xFFu) != (u32)endd[jj])
            u[jj] = __hip_atomic_load(&acc[aIdx], RLX, AGENT);
          em[jj] = __uint_as_float((u32)u[jj]);
          ev[jj] = __uint_as_float(((u32)(u[jj] >> 32)) & ~0xFFu);
        } else {
          em[jj] = NEGINF;
          ev[jj] = 0.f;
        }
      }
      const float zv = (t <= Wn) ? (float)(t + 1) * (szv + bos) : NEGINF;

      float M = zv;
#pragma unroll
      for (int jj = 0; jj < 8; ++jj) M = fmaxf(M, em[jj]);
      float vs = __expf(zv - M);
#pragma unroll
      for (int jj = 0; jj < 8; ++jj) vs += ev[jj] * __expf(em[jj] - M);

      if (act) {
        RESTm[t & 3][lab] = M;
        RESTv[t & 3][lab] = vs;
      }
      LDSF();
      __hip_atomic_store(&rq[h], t, RLX, WG);

      const int tn = t + 1;  // depth-1 prefetch
      if (tn < Tn) {
#pragma unroll
        for (int jj = 0; jj < 8; ++jj)
          if (tn >= endd[jj])
            u[jj] = __hip_atomic_load(
                &acc[(((size_t)jj * 4 + b) * Tn + tn) * Ln + lab], RLX, AGENT);
      }
    }
    return;
  }
}

extern "C" void kernel_launch(void* const* d_in, const int* in_sizes, int n_in,
                              void* d_out, int out_size, void* d_ws,
                              size_t ws_size, hipStream_t stream) {
  const float* seg = (const float*)d_in[0];  // (4,512,512,96) f32
  const float* tr = (const float*)d_in[1];   // (97,96) f32
  float* out = (float*)d_out;                // (4,) f32

  u64* axp = (u64*)d_ws;                 // [4][512][96]
  u64* acc = axp + (size_t)4 * Tn * Ln;  // [8][4][512][96]

  hipLaunchKernelGGL(init_ws, dim3(2048), dim3(256), 0, stream, (u64*)d_ws);
  hipLaunchKernelGGL(semicrf, dim3(4 * NROLE), dim3(512), 0, stream, seg, tr,
                     out, axp, acc);
}